// Round 8
// baseline (391.023 us; speedup 1.0000x reference)
//
#include <hip/hip_runtime.h>
#include <hip/hip_bf16.h>
#include <cstdint>
#include <cstddef>

// B=4, LQ=LK=1024, D=512, H=8. fp32 in/out; bf16 MFMA compute.
// R8: N-tile 256 (wave 64x128, 2x MFMA per staging slot) for proj/big;
// pvw writes fp32 atomicAdd into zeroed d_out (reduce4 dispatch deleted).

typedef __bf16 bf16;
typedef __bf16 bf16x4 __attribute__((ext_vector_type(4)));
typedef __bf16 bf16x8 __attribute__((ext_vector_type(8)));
typedef float f32x4 __attribute__((ext_vector_type(4)));

__device__ inline void gload_lds16(const void* g, void* l) {
  __builtin_amdgcn_global_load_lds(
      (const __attribute__((address_space(1))) void*)g,
      (__attribute__((address_space(3))) void*)l, 16, 0, 0);
}

// Tile body: C[128,NT] at (m0,n0) of scale*(A . B^T). BK=64, 256 thr, 4 waves
// as 2x2, wave tile 64 x NT/2. LDS swizzle: 16B-chunk c of row r at c^(r&7).
// MODE 0: C = acc*scale. MODE 1: P = maskbit ? exp(acc*scale) : 0; rowsums.
template <int NT, typename CT, int MODE>
__device__ __forceinline__ void gemm_body(
    bf16* As, bf16* Bs,
    const bf16* __restrict__ A, const bf16* __restrict__ B, CT* __restrict__ C,
    int K, int lda, int ldb, int ldc, int m0, int n0, float scale,
    const unsigned* __restrict__ mrow, float* __restrict__ sumrow)
{
  constexpr int NW = NT / 32;           // B-frags per wave (4 or 8)
  const int t = threadIdx.x;
  const int lane = t & 63, w = t >> 6;
  const int wm = w >> 1, wn = w & 1;

  const int srow = t >> 3;                       // 0..31
  const int schunk = (t & 7) ^ (srow & 7);       // swizzled source chunk
  const bf16* Ag = A + (size_t)(m0 + srow) * lda + schunk * 8;
  const bf16* Bg = B + (size_t)(n0 + srow) * ldb + schunk * 8;
  bf16* Als = As + t * 8;
  bf16* Bls = Bs + t * 8;

  f32x4 acc[4][NW] = {};
  const int rr = lane & 15;
  const int q4 = lane >> 4;

  const int kIters = K >> 6;
  for (int kt = 0; kt < kIters; ++kt) {
    __syncthreads();
#pragma unroll
    for (int i = 0; i < 4; ++i)
      gload_lds16(Ag + (size_t)(32 * i) * lda, Als + i * 2048);
#pragma unroll
    for (int i = 0; i < NT / 32; ++i)
      gload_lds16(Bg + (size_t)(32 * i) * ldb, Bls + i * 2048);
    Ag += 64; Bg += 64;
    __syncthreads();

#pragma unroll
    for (int kk = 0; kk < 2; ++kk) {
      bf16x8 af[4], bfr[NW];
      const int ck = kk * 4 + q4;
#pragma unroll
      for (int r = 0; r < 4; ++r) {
        const int R = wm * 64 + r * 16 + rr;
        af[r] = *(const bf16x8*)(As + R * 64 + ((ck ^ (R & 7)) << 3));
      }
#pragma unroll
      for (int c = 0; c < NW; ++c) {
        const int R = wn * (NT / 2) + c * 16 + rr;
        bfr[c] = *(const bf16x8*)(Bs + R * 64 + ((ck ^ (R & 7)) << 3));
      }
#pragma unroll
      for (int r = 0; r < 4; ++r)
#pragma unroll
        for (int c = 0; c < NW; ++c)
          acc[r][c] = __builtin_amdgcn_mfma_f32_16x16x32_bf16(af[r], bfr[c], acc[r][c], 0, 0, 0);
    }
  }

  // C/D frag: col = lane&15, row = (lane>>4)*4 + reg
  if (MODE == 0) {
#pragma unroll
    for (int r = 0; r < 4; ++r) {
#pragma unroll
      for (int c = 0; c < NW; ++c) {
        const int gr0 = m0 + wm * 64 + r * 16 + (q4 << 2);
        const int gc = n0 + wn * (NT / 2) + c * 16 + rr;
#pragma unroll
        for (int i = 0; i < 4; ++i)
          C[(size_t)(gr0 + i) * ldc + gc] = (CT)(acc[r][c][i] * scale);
      }
    }
  } else {
    const int cb0 = (n0 + wn * (NT / 2)) >> 5;
#pragma unroll
    for (int r = 0; r < 4; ++r) {
#pragma unroll
      for (int i = 0; i < 4; ++i) {
        const int row = m0 + wm * 64 + r * 16 + (q4 << 2) + i;
        unsigned mw[NW / 2];
#pragma unroll
        for (int j = 0; j < NW / 2; ++j)
          mw[j] = mrow[(row << 5) + cb0 + j];
        float ps = 0.0f;
#pragma unroll
        for (int c = 0; c < NW; ++c) {
          const int gc = n0 + wn * (NT / 2) + c * 16 + rr;
          const unsigned bit = (mw[c >> 1] >> (((c & 1) << 4) + rr)) & 1u;
          float p = bit ? __expf(acc[r][c][i] * scale) : 0.0f;
          C[(size_t)row * ldc + gc] = (CT)p;
          ps += p;
        }
        ps += __shfl_xor(ps, 1); ps += __shfl_xor(ps, 2);
        ps += __shfl_xor(ps, 4); ps += __shfl_xor(ps, 8);
        if (rr == 0) atomicAdd(sumrow + row, ps);
      }
    }
  }
}

// ---- Dispatch 1: prep (cvt5 + cvtT + pack_mask + zero sums). grid 12832. ----
__global__ __launch_bounds__(256) void prep_kernel(
    const float* __restrict__ x, const float* __restrict__ st,
    const float* __restrict__ Wq, const float* __restrict__ Wk,
    const float* __restrict__ Wp, const float* __restrict__ Wv,
    const int* __restrict__ mask,
    bf16* __restrict__ xb, bf16* __restrict__ stb, bf16* __restrict__ wqb,
    bf16* __restrict__ wkb, bf16* __restrict__ wpb, bf16* __restrict__ WvT,
    unsigned* __restrict__ mbits, float* __restrict__ sums)
{
  const int lin = blockIdx.x;
  const int t = threadIdx.x;
  if (lin < 10240) {
    const float* s; bf16* d;
    switch (lin >> 11) {
      case 0: s = x; d = xb; break;
      case 1: s = st; d = stb; break;
      case 2: s = Wq; d = wqb; break;
      case 3: s = Wk; d = wkb; break;
      default: s = Wp; d = wpb; break;
    }
    const int i = ((lin & 2047) * 256 + t) * 4;
    float4 v = *(const float4*)(s + i);
    bf16x4 o;
    o[0] = (bf16)v.x; o[1] = (bf16)v.y; o[2] = (bf16)v.z; o[3] = (bf16)v.w;
    *(bf16x4*)(d + i) = o;
  } else if (lin < 12288) {
    // WvT[h][d][e'] = Wv[h][e'][d]
    const int gid = (lin - 10240) * 256 + t;      // [0, 524288)
    const int e0 = (gid & 127) * 4;
    const int d = (gid >> 7) & 511;
    const int h = gid >> 16;
    const float* src = Wv + (size_t)h * 262144 + (size_t)e0 * 512 + d;
    bf16x4 o;
    o[0] = (bf16)src[0];
    o[1] = (bf16)src[512];
    o[2] = (bf16)src[1024];
    o[3] = (bf16)src[1536];
    *(bf16x4*)(WvT + (size_t)h * 262144 + (size_t)d * 512 + e0) = o;
  } else if (lin < 12800) {
    const int gid = (lin - 12288) * 256 + t;      // [0, 131072)
    const int* src = mask + (size_t)gid * 32;
    unsigned bits = 0;
#pragma unroll
    for (int j = 0; j < 32; j += 4) {
      int4 v = *(const int4*)(src + j);
      if (v.x) bits |= 1u << j;
      if (v.y) bits |= 1u << (j + 1);
      if (v.z) bits |= 1u << (j + 2);
      if (v.w) bits |= 1u << (j + 3);
    }
    mbits[gid] = bits;
  } else {
    const int i = ((lin - 12800) * 256 + t) * 4;  // [0, 32768) floats
    *(float4*)(sums + i) = make_float4(0.f, 0.f, 0.f, 0.f);
  }
}

// ---- Dispatch 2: proj (q/k projections + U = Wp_h.Wv_h). grid 1088. ----
__global__ __launch_bounds__(256) void proj_kernel(
    const bf16* __restrict__ xb, const bf16* __restrict__ stb,
    const bf16* __restrict__ wqb, const bf16* __restrict__ wkb,
    const bf16* __restrict__ wpb, const bf16* __restrict__ WvT,
    bf16* __restrict__ q, bf16* __restrict__ k, bf16* __restrict__ U)
{
  __shared__ bf16 As[128 * 64];
  __shared__ bf16 Bs[256 * 64];
  const int lin = blockIdx.x;
  if (lin < 1024) {
    // q/k: (job,z) grouped per XCD; 16 tiles (8 l x 2 n of 256)
    const int jz = ((lin >> 7) << 3) | (lin & 7);  // [0,64)
    const int j = (lin >> 3) & 15;
    const int job = jz >> 5;
    const int zz = jz & 31;
    const size_t zb = zz >> 3, zh = zz & 7;
    const bf16* Ain = (job == 0) ? xb : stb;
    const bf16* W = (job == 0) ? wqb : wkb;
    bf16* Cout = (job == 0) ? q : k;
    gemm_body<256, bf16, 0>(As, Bs, Ain + zb * 524288, W + zh * 262144,
        Cout + zb * 4194304 + zh * 524288, 512, 512, 512, 512,
        (j >> 1) * 128, (j & 1) * 256, 1.0f, nullptr, nullptr);
  } else {
    // U_h[e,d] = sum_e' Wp[e, h*512+e'] * WvT_h[d, e']  (8 tiles: 4 m x 2 n)
    const int lin2 = lin - 1024;                   // [0,64)
    const int h = lin2 >> 3;
    const int j = lin2 & 7;
    gemm_body<256, bf16, 0>(As, Bs, wpb + (size_t)h * 512, WvT + (size_t)h * 262144,
        U + (size_t)h * 262144, 512, 4096, 512, 512,
        (j >> 1) * 128, (j & 1) * 256, 1.0f, nullptr, nullptr);
  }
}

// ---- Dispatch 3: big (scores+exp+rowsum, and VWT = U.states^T). grid 1536. ----
__global__ __launch_bounds__(256) void big_kernel(
    const bf16* __restrict__ q, const bf16* __restrict__ k,
    const bf16* __restrict__ U, const bf16* __restrict__ stb,
    bf16* __restrict__ P, bf16* __restrict__ VWT,
    const unsigned* __restrict__ mbits, float* __restrict__ sums, float scale)
{
  __shared__ bf16 As[128 * 64];
  __shared__ bf16 Bs[256 * 64];
  const int lin = blockIdx.x;
  if (lin < 1024) {
    // scores: z in [0,32) same-XCD; 32 tiles (8 l x 4 n of 256)
    const int z = ((lin >> 8) << 3) | (lin & 7);
    const int j = (lin >> 3) & 31;
    const int zb = z >> 3, zh = z & 7;
    const bf16* A = q + (size_t)zb * 4194304 + (size_t)zh * 524288;
    const bf16* B = k + (size_t)zb * 4194304 + (size_t)zh * 524288;
    bf16* C = P + (size_t)zb * 8388608 + (size_t)zh * 1048576;
    const unsigned* mrow = mbits + ((size_t)zb << 15);
    float* sumrow = sums + ((size_t)z << 10);
    gemm_body<256, bf16, 1>(As, Bs, A, B, C, 512, 512, 512, 1024,
                            (j >> 2) * 128, (j & 3) * 256, scale, mrow, sumrow);
  } else {
    // VWT[b,h][e,s] = U_h . states_b^T : 16 tiles (4 m x 4 n of 256)
    const int lin2 = lin - 1024;                   // [0,512)
    const int z = ((lin2 >> 7) << 3) | (lin2 & 7);
    const int j = (lin2 >> 3) & 15;
    const int zb = z >> 3, zh = z & 7;
    gemm_body<256, bf16, 0>(As, Bs, U + (size_t)zh * 262144, stb + (size_t)zb * 524288,
        VWT + (size_t)zb * 4194304 + (size_t)zh * 524288, 512, 512, 512, 1024,
        (j >> 2) * 128, (j & 3) * 256, 1.0f, nullptr, nullptr);
  }
}

// ---- Dispatch 4: pvw — atomicAdd_{h in pair} sinv_h ⊙ (P_h·VWT_h^T) into out.
// grid 512 (z in [0,16) XCD-grouped, 32 tiles = 8 l x 4 e). fp32 out. ----
__global__ __launch_bounds__(256) void pvw_kernel(
    const bf16* __restrict__ P, const bf16* __restrict__ VWT,
    const float* __restrict__ sums, float* __restrict__ out)
{
  __shared__ bf16 As[128 * 64];
  __shared__ bf16 Bs[128 * 64];
  const int lin = blockIdx.x;
  const int z = ((lin >> 8) << 3) | (lin & 7);    // [0,16)
  const int j = (lin >> 3) & 31;
  const int zb = z >> 2, hp = z & 3;
  const int m0 = (j >> 2) * 128, n0 = (j & 3) * 128;
  const int t = threadIdx.x;
  const int lane = t & 63, w = t >> 6;
  const int wm = w >> 1, wn = w & 1;
  const int srow = t >> 3, schunk = (t & 7) ^ (srow & 7);
  const int rr = lane & 15, q4 = lane >> 4;
  bf16* Als = As + t * 8;
  bf16* Bls = Bs + t * 8;

  f32x4 accO[4][4] = {};

#pragma unroll
  for (int hh = 0; hh < 2; ++hh) {
    const int h = hp * 2 + hh;
    const bf16* Ag = P + (size_t)zb * 8388608 + (size_t)h * 1048576
                       + (size_t)(m0 + srow) * 1024 + schunk * 8;
    const bf16* Bg = VWT + (size_t)zb * 4194304 + (size_t)h * 524288
                        + (size_t)(n0 + srow) * 1024 + schunk * 8;
    f32x4 acc[4][4] = {};
    for (int kt = 0; kt < 16; ++kt) {
      __syncthreads();
#pragma unroll
      for (int i = 0; i < 4; ++i) {
        gload_lds16(Ag + (size_t)(32 * i) * 1024, Als + i * 2048);
        gload_lds16(Bg + (size_t)(32 * i) * 1024, Bls + i * 2048);
      }
      Ag += 64; Bg += 64;
      __syncthreads();
#pragma unroll
      for (int kk = 0; kk < 2; ++kk) {
        bf16x8 af[4], bfr[4];
        const int ck = kk * 4 + q4;
#pragma unroll
        for (int r = 0; r < 4; ++r) {
          const int R = wm * 64 + r * 16 + rr;
          af[r] = *(const bf16x8*)(As + R * 64 + ((ck ^ (R & 7)) << 3));
        }
#pragma unroll
        for (int c = 0; c < 4; ++c) {
          const int R = wn * 64 + c * 16 + rr;
          bfr[c] = *(const bf16x8*)(Bs + R * 64 + ((ck ^ (R & 7)) << 3));
        }
#pragma unroll
        for (int r = 0; r < 4; ++r)
#pragma unroll
          for (int c = 0; c < 4; ++c)
            acc[r][c] = __builtin_amdgcn_mfma_f32_16x16x32_bf16(af[r], bfr[c], acc[r][c], 0, 0, 0);
      }
    }
    const float* srs = sums + ((size_t)zb * 8 + h) * 1024;
#pragma unroll
    for (int r = 0; r < 4; ++r) {
#pragma unroll
      for (int i = 0; i < 4; ++i) {
        const float inv = 1.0f / srs[m0 + wm * 64 + r * 16 + (q4 << 2) + i];
#pragma unroll
        for (int c = 0; c < 4; ++c)
          accO[r][c][i] += acc[r][c][i] * inv;
      }
    }
  }

  float* Cp = out + (size_t)zb * 524288;
#pragma unroll
  for (int r = 0; r < 4; ++r) {
#pragma unroll
    for (int c = 0; c < 4; ++c) {
      const int gr0 = m0 + wm * 64 + r * 16 + (q4 << 2);
      const int gc = n0 + wn * 64 + c * 16 + rr;
#pragma unroll
      for (int i = 0; i < 4; ++i)
        atomicAdd(Cp + (size_t)(gr0 + i) * 512 + gc, accO[r][c][i]);
    }
  }
}

extern "C" void kernel_launch(void* const* d_in, const int* in_sizes, int n_in,
                              void* d_out, int out_size, void* d_ws, size_t ws_size,
                              hipStream_t stream) {
  const float* x    = (const float*)d_in[0];
  const float* st   = (const float*)d_in[1];
  const int*   mask = (const int*)d_in[2];
  const float* Wq   = (const float*)d_in[3];
  const float* Wk   = (const float*)d_in[4];
  const float* Wv   = (const float*)d_in[5];
  const float* Wp   = (const float*)d_in[6];
  float* out = (float*)d_out;

  char* ws = (char*)d_ws;
  const size_t MB = 1048576;
  bf16* xb  = (bf16*)(ws);               // 4MB
  bf16* stb = (bf16*)(ws + 4 * MB);      // 4MB (live through VWT)
  bf16* wqb = (bf16*)(ws + 8 * MB);      // 4MB
  bf16* wkb = (bf16*)(ws + 12 * MB);     // 4MB
  bf16* wpb = (bf16*)(ws + 16 * MB);     // 4MB
  bf16* WvT = (bf16*)(ws + 20 * MB);     // 4MB [8,512,512] transposed
  bf16* U   = (bf16*)(ws + 24 * MB);     // 4MB [8,512,512] Wp_h.Wv_h
  bf16* q   = (bf16*)(ws + 28 * MB);     // 32MB
  bf16* k   = (bf16*)(ws + 60 * MB);     // 32MB
  bf16* VWT = (bf16*)(ws + 92 * MB);     // 32MB [4,8,512,1024]
  bf16* sc  = (bf16*)(ws + 124 * MB);    // 64MB P = exp(scores)
  unsigned* mbits = (unsigned*)(ws + 188 * MB);  // 512KB
  float*    sums  = (float*)(ws + 189 * MB);     // 128KB

  dim3 blk(256);
  const float scale = 0.04419417382415922f;  // 1/sqrt(512)

  // zero d_out early (pvw accumulates into it atomically)
  hipMemsetAsync(d_out, 0, (size_t)out_size * sizeof(float), stream);

  prep_kernel<<<dim3(12832), blk, 0, stream>>>(x, st, Wq, Wk, Wp, Wv, mask,
      xb, stb, wqb, wkb, wpb, WvT, mbits, sums);

  proj_kernel<<<dim3(1088), blk, 0, stream>>>(xb, stb, wqb, wkb, wpb, WvT,
      q, k, U);

  big_kernel<<<dim3(1536), blk, 0, stream>>>(q, k, U, stb, sc, VWT,
      mbits, sums, scale);

  pvw_kernel<<<dim3(512), blk, 0, stream>>>(sc, VWT, sums, out);
}

// Round 9
// 298.399 us; speedup vs baseline: 1.3104x; 1.3104x over previous
//
#include <hip/hip_runtime.h>
#include <hip/hip_bf16.h>
#include <cstdint>
#include <cstddef>

// B=4, LQ=LK=1024, D=512, H=8. fp32 in/out; bf16 MFMA compute.
// R9 = R7 structure (NT=128, VGPR 80, 5 blocks/CU) + pvw atomicAdd into
// zeroed d_out (reduce4 deleted). R8's NT=256 occupancy cliff reverted.

typedef __bf16 bf16;
typedef __bf16 bf16x4 __attribute__((ext_vector_type(4)));
typedef __bf16 bf16x8 __attribute__((ext_vector_type(8)));
typedef float f32x4 __attribute__((ext_vector_type(4)));

__device__ inline void gload_lds16(const void* g, void* l) {
  __builtin_amdgcn_global_load_lds(
      (const __attribute__((address_space(1))) void*)g,
      (__attribute__((address_space(3))) void*)l, 16, 0, 0);
}

// Tile body: C[128,128] at (m0,n0) of scale*(A . B^T). BK=64, 256 thr.
// LDS swizzle: global 16B-chunk c of row r lives at slot c ^ (r&7).
// MODE 0: C = acc*scale (CT).
// MODE 1: P = maskbit ? exp(acc*scale) : 0 -> C (bf16); atomicAdd row sums.
template <typename CT, int MODE>
__device__ __forceinline__ void gemm_body(
    bf16* As, bf16* Bs,
    const bf16* __restrict__ A, const bf16* __restrict__ B, CT* __restrict__ C,
    int K, int lda, int ldb, int ldc, int m0, int n0, float scale,
    const unsigned* __restrict__ mrow, float* __restrict__ sumrow)
{
  const int t = threadIdx.x;
  const int lane = t & 63, w = t >> 6;
  const int wm = w >> 1, wn = w & 1;

  const int srow = t >> 3;                       // 0..31
  const int schunk = (t & 7) ^ (srow & 7);       // swizzled source chunk
  const bf16* Ag = A + (size_t)(m0 + srow) * lda + schunk * 8;
  const bf16* Bg = B + (size_t)(n0 + srow) * ldb + schunk * 8;
  bf16* Als = As + t * 8;
  bf16* Bls = Bs + t * 8;

  f32x4 acc[4][4] = {};
  const int rr = lane & 15;
  const int q4 = lane >> 4;

  const int kIters = K >> 6;
  for (int kt = 0; kt < kIters; ++kt) {
    __syncthreads();
#pragma unroll
    for (int i = 0; i < 4; ++i) {
      gload_lds16(Ag + (size_t)(32 * i) * lda, Als + i * 2048);
      gload_lds16(Bg + (size_t)(32 * i) * ldb, Bls + i * 2048);
    }
    Ag += 64; Bg += 64;
    __syncthreads();

#pragma unroll
    for (int kk = 0; kk < 2; ++kk) {
      bf16x8 af[4], bfr[4];
      const int ck = kk * 4 + q4;
#pragma unroll
      for (int r = 0; r < 4; ++r) {
        const int R = wm * 64 + r * 16 + rr;
        af[r] = *(const bf16x8*)(As + R * 64 + ((ck ^ (R & 7)) << 3));
      }
#pragma unroll
      for (int c = 0; c < 4; ++c) {
        const int R = wn * 64 + c * 16 + rr;
        bfr[c] = *(const bf16x8*)(Bs + R * 64 + ((ck ^ (R & 7)) << 3));
      }
#pragma unroll
      for (int r = 0; r < 4; ++r)
#pragma unroll
        for (int c = 0; c < 4; ++c)
          acc[r][c] = __builtin_amdgcn_mfma_f32_16x16x32_bf16(af[r], bfr[c], acc[r][c], 0, 0, 0);
    }
  }

  // C/D frag: col = lane&15, row = (lane>>4)*4 + reg
  if (MODE == 0) {
#pragma unroll
    for (int r = 0; r < 4; ++r) {
#pragma unroll
      for (int c = 0; c < 4; ++c) {
        const int gr0 = m0 + wm * 64 + r * 16 + (q4 << 2);
        const int gc = n0 + wn * 64 + c * 16 + rr;
#pragma unroll
        for (int i = 0; i < 4; ++i)
          C[(size_t)(gr0 + i) * ldc + gc] = (CT)(acc[r][c][i] * scale);
      }
    }
  } else {
    const int cb0 = (n0 + wn * 64) >> 5;
#pragma unroll
    for (int r = 0; r < 4; ++r) {
#pragma unroll
      for (int i = 0; i < 4; ++i) {
        const int row = m0 + wm * 64 + r * 16 + (q4 << 2) + i;
        const unsigned mw0 = mrow[(row << 5) + cb0];
        const unsigned mw1 = mrow[(row << 5) + cb0 + 1];
        float ps = 0.0f;
#pragma unroll
        for (int c = 0; c < 4; ++c) {
          const int gc = n0 + wn * 64 + c * 16 + rr;
          const unsigned mw = (c >= 2) ? mw1 : mw0;
          const unsigned bit = (mw >> (((c & 1) << 4) + rr)) & 1u;
          float p = bit ? __expf(acc[r][c][i] * scale) : 0.0f;
          C[(size_t)row * ldc + gc] = (CT)p;
          ps += p;
        }
        ps += __shfl_xor(ps, 1); ps += __shfl_xor(ps, 2);
        ps += __shfl_xor(ps, 4); ps += __shfl_xor(ps, 8);
        if (rr == 0) atomicAdd(sumrow + row, ps);
      }
    }
  }
}

// ---- Dispatch 1: prep (cvt5 + cvtT + pack_mask + zero sums). grid 12832. ----
__global__ __launch_bounds__(256) void prep_kernel(
    const float* __restrict__ x, const float* __restrict__ st,
    const float* __restrict__ Wq, const float* __restrict__ Wk,
    const float* __restrict__ Wp, const float* __restrict__ Wv,
    const int* __restrict__ mask,
    bf16* __restrict__ xb, bf16* __restrict__ stb, bf16* __restrict__ wqb,
    bf16* __restrict__ wkb, bf16* __restrict__ wpb, bf16* __restrict__ WvT,
    unsigned* __restrict__ mbits, float* __restrict__ sums)
{
  const int lin = blockIdx.x;
  const int t = threadIdx.x;
  if (lin < 10240) {
    const float* s; bf16* d;
    switch (lin >> 11) {
      case 0: s = x; d = xb; break;
      case 1: s = st; d = stb; break;
      case 2: s = Wq; d = wqb; break;
      case 3: s = Wk; d = wkb; break;
      default: s = Wp; d = wpb; break;
    }
    const int i = ((lin & 2047) * 256 + t) * 4;
    float4 v = *(const float4*)(s + i);
    bf16x4 o;
    o[0] = (bf16)v.x; o[1] = (bf16)v.y; o[2] = (bf16)v.z; o[3] = (bf16)v.w;
    *(bf16x4*)(d + i) = o;
  } else if (lin < 12288) {
    // WvT[h][d][e'] = Wv[h][e'][d]
    const int gid = (lin - 10240) * 256 + t;      // [0, 524288)
    const int e0 = (gid & 127) * 4;
    const int d = (gid >> 7) & 511;
    const int h = gid >> 16;
    const float* src = Wv + (size_t)h * 262144 + (size_t)e0 * 512 + d;
    bf16x4 o;
    o[0] = (bf16)src[0];
    o[1] = (bf16)src[512];
    o[2] = (bf16)src[1024];
    o[3] = (bf16)src[1536];
    *(bf16x4*)(WvT + (size_t)h * 262144 + (size_t)d * 512 + e0) = o;
  } else if (lin < 12800) {
    const int gid = (lin - 12288) * 256 + t;      // [0, 131072)
    const int* src = mask + (size_t)gid * 32;
    unsigned bits = 0;
#pragma unroll
    for (int j = 0; j < 32; j += 4) {
      int4 v = *(const int4*)(src + j);
      if (v.x) bits |= 1u << j;
      if (v.y) bits |= 1u << (j + 1);
      if (v.z) bits |= 1u << (j + 2);
      if (v.w) bits |= 1u << (j + 3);
    }
    mbits[gid] = bits;
  } else {
    const int i = ((lin - 12800) * 256 + t) * 4;  // [0, 32768) floats
    *(float4*)(sums + i) = make_float4(0.f, 0.f, 0.f, 0.f);
  }
}

// ---- Dispatch 2: proj (q/k projections + U = Wp_h.Wv_h). grid 2176. ----
__global__ __launch_bounds__(256) void proj_kernel(
    const bf16* __restrict__ xb, const bf16* __restrict__ stb,
    const bf16* __restrict__ wqb, const bf16* __restrict__ wkb,
    const bf16* __restrict__ wpb, const bf16* __restrict__ WvT,
    bf16* __restrict__ q, bf16* __restrict__ k, bf16* __restrict__ U)
{
  __shared__ bf16 As[128 * 64];
  __shared__ bf16 Bs[128 * 64];
  const int lin = blockIdx.x;
  if (lin < 2048) {
    // XCD swizzle: g = job*32+zz grouped per XCD
    const int g = ((lin >> 8) << 3) | (lin & 7);   // [0,64)
    const int tile = (lin >> 3) & 31;
    const int job = g >> 5;
    const int zz = g & 31;
    const size_t zb = zz >> 3, zh = zz & 7;
    const bf16* Ain = (job == 0) ? xb : stb;
    const bf16* W = (job == 0) ? wqb : wkb;
    bf16* Cout = (job == 0) ? q : k;
    gemm_body<bf16, 0>(As, Bs, Ain + zb * 524288, W + zh * 262144,
        Cout + zb * 4194304 + zh * 524288, 512, 512, 512, 512,
        (tile >> 2) * 128, (tile & 3) * 128, 1.0f, nullptr, nullptr);
  } else {
    // U_h[e,d] = sum_e' Wp[e, h*512+e'] * WvT_h[d, e']
    const int lin2 = lin - 2048;                   // [0,128)
    const int h = lin2 >> 4;
    const int tile = lin2 & 15;
    gemm_body<bf16, 0>(As, Bs, wpb + (size_t)h * 512, WvT + (size_t)h * 262144,
        U + (size_t)h * 262144, 512, 4096, 512, 512,
        (tile >> 2) * 128, (tile & 3) * 128, 1.0f, nullptr, nullptr);
  }
}

// ---- Dispatch 3: big (scores+exp+rowsum, and VWT = U.states^T). grid 3072. ----
__global__ __launch_bounds__(256) void big_kernel(
    const bf16* __restrict__ q, const bf16* __restrict__ k,
    const bf16* __restrict__ U, const bf16* __restrict__ stb,
    bf16* __restrict__ P, bf16* __restrict__ VWT,
    const unsigned* __restrict__ mbits, float* __restrict__ sums, float scale)
{
  __shared__ bf16 As[128 * 64];
  __shared__ bf16 Bs[128 * 64];
  const int lin = blockIdx.x;
  if (lin < 2048) {
    // scores: z in [0,32), 64 tiles (8x8); same-z blocks on one XCD
    const int z = ((lin >> 9) << 3) | (lin & 7);
    const int j = (lin >> 3) & 63;
    const int zb = z >> 3, zh = z & 7;
    const bf16* A = q + (size_t)zb * 4194304 + (size_t)zh * 524288;
    const bf16* B = k + (size_t)zb * 4194304 + (size_t)zh * 524288;
    bf16* C = P + (size_t)zb * 8388608 + (size_t)zh * 1048576;
    const unsigned* mrow = mbits + ((size_t)zb << 15);
    float* sumrow = sums + ((size_t)z << 10);
    gemm_body<bf16, 1>(As, Bs, A, B, C, 512, 512, 512, 1024,
                       (j >> 3) * 128, (j & 7) * 128, scale, mrow, sumrow);
  } else {
    // VWT[b,h][e,s] = U_h . states_b^T : z in [0,32), 32 tiles (8 n x 4 m)
    const int lin2 = lin - 2048;
    const int z = ((lin2 >> 8) << 3) | (lin2 & 7);
    const int j = (lin2 >> 3) & 31;
    const int zb = z >> 3, zh = z & 7;
    gemm_body<bf16, 0>(As, Bs, U + (size_t)zh * 262144, stb + (size_t)zb * 524288,
        VWT + (size_t)zb * 4194304 + (size_t)zh * 524288, 512, 512, 512, 1024,
        (j >> 3) * 128, (j & 7) * 128, 1.0f, nullptr, nullptr);
  }
}

// ---- Dispatch 4: pvw — atomicAdd_{h in pair} sinv_h ⊙ (P_h·VWT_h^T) into out.
// grid 512 (z in [0,16) XCD-grouped, 32 tiles = 8 l x 4 e). fp32 out. ----
__global__ __launch_bounds__(256) void pvw_kernel(
    const bf16* __restrict__ P, const bf16* __restrict__ VWT,
    const float* __restrict__ sums, float* __restrict__ out)
{
  __shared__ bf16 As[128 * 64];
  __shared__ bf16 Bs[128 * 64];
  const int lin = blockIdx.x;
  const int z = ((lin >> 8) << 3) | (lin & 7);    // [0,16)
  const int j = (lin >> 3) & 31;
  const int zb = z >> 2, hp = z & 3;
  const int m0 = (j >> 2) * 128, n0 = (j & 3) * 128;
  const int t = threadIdx.x;
  const int lane = t & 63, w = t >> 6;
  const int wm = w >> 1, wn = w & 1;
  const int srow = t >> 3, schunk = (t & 7) ^ (srow & 7);
  const int rr = lane & 15, q4 = lane >> 4;
  bf16* Als = As + t * 8;
  bf16* Bls = Bs + t * 8;

  f32x4 accO[4][4] = {};

#pragma unroll
  for (int hh = 0; hh < 2; ++hh) {
    const int h = hp * 2 + hh;
    const bf16* Ag = P + (size_t)zb * 8388608 + (size_t)h * 1048576
                       + (size_t)(m0 + srow) * 1024 + schunk * 8;
    const bf16* Bg = VWT + (size_t)zb * 4194304 + (size_t)h * 524288
                        + (size_t)(n0 + srow) * 1024 + schunk * 8;
    f32x4 acc[4][4] = {};
    for (int kt = 0; kt < 16; ++kt) {
      __syncthreads();
#pragma unroll
      for (int i = 0; i < 4; ++i) {
        gload_lds16(Ag + (size_t)(32 * i) * 1024, Als + i * 2048);
        gload_lds16(Bg + (size_t)(32 * i) * 1024, Bls + i * 2048);
      }
      Ag += 64; Bg += 64;
      __syncthreads();
#pragma unroll
      for (int kk = 0; kk < 2; ++kk) {
        bf16x8 af[4], bfr[4];
        const int ck = kk * 4 + q4;
#pragma unroll
        for (int r = 0; r < 4; ++r) {
          const int R = wm * 64 + r * 16 + rr;
          af[r] = *(const bf16x8*)(As + R * 64 + ((ck ^ (R & 7)) << 3));
        }
#pragma unroll
        for (int c = 0; c < 4; ++c) {
          const int R = wn * 64 + c * 16 + rr;
          bfr[c] = *(const bf16x8*)(Bs + R * 64 + ((ck ^ (R & 7)) << 3));
        }
#pragma unroll
        for (int r = 0; r < 4; ++r)
#pragma unroll
          for (int c = 0; c < 4; ++c)
            acc[r][c] = __builtin_amdgcn_mfma_f32_16x16x32_bf16(af[r], bfr[c], acc[r][c], 0, 0, 0);
      }
    }
    const float* srs = sums + ((size_t)zb * 8 + h) * 1024;
#pragma unroll
    for (int r = 0; r < 4; ++r) {
#pragma unroll
      for (int i = 0; i < 4; ++i) {
        const float inv = 1.0f / srs[m0 + wm * 64 + r * 16 + (q4 << 2) + i];
#pragma unroll
        for (int c = 0; c < 4; ++c)
          accO[r][c][i] += acc[r][c][i] * inv;
      }
    }
  }

  float* Cp = out + (size_t)zb * 524288;
#pragma unroll
  for (int r = 0; r < 4; ++r) {
#pragma unroll
    for (int c = 0; c < 4; ++c) {
      const int gr0 = m0 + wm * 64 + r * 16 + (q4 << 2);
      const int gc = n0 + wn * 64 + c * 16 + rr;
#pragma unroll
      for (int i = 0; i < 4; ++i)
        atomicAdd(Cp + (size_t)(gr0 + i) * 512 + gc, accO[r][c][i]);
    }
  }
}

extern "C" void kernel_launch(void* const* d_in, const int* in_sizes, int n_in,
                              void* d_out, int out_size, void* d_ws, size_t ws_size,
                              hipStream_t stream) {
  const float* x    = (const float*)d_in[0];
  const float* st   = (const float*)d_in[1];
  const int*   mask = (const int*)d_in[2];
  const float* Wq   = (const float*)d_in[3];
  const float* Wk   = (const float*)d_in[4];
  const float* Wv   = (const float*)d_in[5];
  const float* Wp   = (const float*)d_in[6];
  float* out = (float*)d_out;

  char* ws = (char*)d_ws;
  const size_t MB = 1048576;
  bf16* xb  = (bf16*)(ws);               // 4MB
  bf16* stb = (bf16*)(ws + 4 * MB);      // 4MB (live through VWT)
  bf16* wqb = (bf16*)(ws + 8 * MB);      // 4MB
  bf16* wkb = (bf16*)(ws + 12 * MB);     // 4MB
  bf16* wpb = (bf16*)(ws + 16 * MB);     // 4MB
  bf16* WvT = (bf16*)(ws + 20 * MB);     // 4MB [8,512,512] transposed
  bf16* U   = (bf16*)(ws + 24 * MB);     // 4MB [8,512,512] Wp_h.Wv_h
  bf16* q   = (bf16*)(ws + 28 * MB);     // 32MB
  bf16* k   = (bf16*)(ws + 60 * MB);     // 32MB
  bf16* VWT = (bf16*)(ws + 92 * MB);     // 32MB [4,8,512,1024]
  bf16* sc  = (bf16*)(ws + 124 * MB);    // 64MB P = exp(scores)
  unsigned* mbits = (unsigned*)(ws + 188 * MB);  // 512KB
  float*    sums  = (float*)(ws + 189 * MB);     // 128KB

  dim3 blk(256);
  const float scale = 0.04419417382415922f;  // 1/sqrt(512)

  // zero d_out early (pvw accumulates into it atomically)
  hipMemsetAsync(d_out, 0, (size_t)out_size * sizeof(float), stream);

  prep_kernel<<<dim3(12832), blk, 0, stream>>>(x, st, Wq, Wk, Wp, Wv, mask,
      xb, stb, wqb, wkb, wpb, WvT, mbits, sums);

  proj_kernel<<<dim3(2176), blk, 0, stream>>>(xb, stb, wqb, wkb, wpb, WvT,
      q, k, U);

  big_kernel<<<dim3(3072), blk, 0, stream>>>(q, k, U, stb, sc, VWT,
      mbits, sums, scale);

  pvw_kernel<<<dim3(512), blk, 0, stream>>>(sc, VWT, sums, out);
}

// Round 11
// 288.773 us; speedup vs baseline: 1.3541x; 1.0333x over previous
//
#include <hip/hip_runtime.h>
#include <hip/hip_bf16.h>
#include <cstdint>
#include <cstddef>

// B=4, LQ=LK=1024, D=512, H=8. fp32 in/out; bf16 MFMA compute.
// R11 = R7 (all-bf16; fp8 reverted — e4m3 3.6% rel err fails the 2% bar) +
// pvw split to one-h-per-block (1024 blocks, 2x resident waves) with bf16
// partials (8 slots, same bytes as 4 fp32 slots) + reduce8.

typedef __bf16 bf16;
typedef __bf16 bf16x4 __attribute__((ext_vector_type(4)));
typedef __bf16 bf16x8 __attribute__((ext_vector_type(8)));
typedef float f32x4 __attribute__((ext_vector_type(4)));

__device__ inline void gload_lds16(const void* g, void* l) {
  __builtin_amdgcn_global_load_lds(
      (const __attribute__((address_space(1))) void*)g,
      (__attribute__((address_space(3))) void*)l, 16, 0, 0);
}

// Tile body: C[128,128] at (m0,n0) of scale*(A . B^T). BK=64, 256 thr.
// LDS swizzle: global 16B-chunk c of row r lives at slot c ^ (r&7).
// MODE 0: C = acc*scale (bf16).
// MODE 1: P = maskbit ? exp(acc*scale) : 0 -> C (bf16); atomicAdd row sums.
template <typename CT, int MODE>
__device__ __forceinline__ void gemm_body(
    bf16* As, bf16* Bs,
    const bf16* __restrict__ A, const bf16* __restrict__ B, CT* __restrict__ C,
    int K, int lda, int ldb, int ldc, int m0, int n0, float scale,
    const unsigned* __restrict__ mrow, float* __restrict__ sumrow)
{
  const int t = threadIdx.x;
  const int lane = t & 63, w = t >> 6;
  const int wm = w >> 1, wn = w & 1;

  const int srow = t >> 3;                       // 0..31
  const int schunk = (t & 7) ^ (srow & 7);       // swizzled source chunk
  const bf16* Ag = A + (size_t)(m0 + srow) * lda + schunk * 8;
  const bf16* Bg = B + (size_t)(n0 + srow) * ldb + schunk * 8;
  bf16* Als = As + t * 8;
  bf16* Bls = Bs + t * 8;

  f32x4 acc[4][4] = {};
  const int rr = lane & 15;
  const int q4 = lane >> 4;

  const int kIters = K >> 6;
  for (int kt = 0; kt < kIters; ++kt) {
    __syncthreads();
#pragma unroll
    for (int i = 0; i < 4; ++i) {
      gload_lds16(Ag + (size_t)(32 * i) * lda, Als + i * 2048);
      gload_lds16(Bg + (size_t)(32 * i) * ldb, Bls + i * 2048);
    }
    Ag += 64; Bg += 64;
    __syncthreads();

#pragma unroll
    for (int kk = 0; kk < 2; ++kk) {
      bf16x8 af[4], bfr[4];
      const int ck = kk * 4 + q4;
#pragma unroll
      for (int r = 0; r < 4; ++r) {
        const int R = wm * 64 + r * 16 + rr;
        af[r] = *(const bf16x8*)(As + R * 64 + ((ck ^ (R & 7)) << 3));
      }
#pragma unroll
      for (int c = 0; c < 4; ++c) {
        const int R = wn * 64 + c * 16 + rr;
        bfr[c] = *(const bf16x8*)(Bs + R * 64 + ((ck ^ (R & 7)) << 3));
      }
#pragma unroll
      for (int r = 0; r < 4; ++r)
#pragma unroll
        for (int c = 0; c < 4; ++c)
          acc[r][c] = __builtin_amdgcn_mfma_f32_16x16x32_bf16(af[r], bfr[c], acc[r][c], 0, 0, 0);
    }
  }

  // C/D frag: col = lane&15, row = (lane>>4)*4 + reg
  if (MODE == 0) {
#pragma unroll
    for (int r = 0; r < 4; ++r) {
#pragma unroll
      for (int c = 0; c < 4; ++c) {
        const int gr0 = m0 + wm * 64 + r * 16 + (q4 << 2);
        const int gc = n0 + wn * 64 + c * 16 + rr;
#pragma unroll
        for (int i = 0; i < 4; ++i)
          C[(size_t)(gr0 + i) * ldc + gc] = (CT)(acc[r][c][i] * scale);
      }
    }
  } else {
    const int cb0 = (n0 + wn * 64) >> 5;
#pragma unroll
    for (int r = 0; r < 4; ++r) {
#pragma unroll
      for (int i = 0; i < 4; ++i) {
        const int row = m0 + wm * 64 + r * 16 + (q4 << 2) + i;
        const unsigned mw0 = mrow[(row << 5) + cb0];
        const unsigned mw1 = mrow[(row << 5) + cb0 + 1];
        float ps = 0.0f;
#pragma unroll
        for (int c = 0; c < 4; ++c) {
          const int gc = n0 + wn * 64 + c * 16 + rr;
          const unsigned mw = (c >= 2) ? mw1 : mw0;
          const unsigned bit = (mw >> (((c & 1) << 4) + rr)) & 1u;
          float p = bit ? __expf(acc[r][c][i] * scale) : 0.0f;
          C[(size_t)row * ldc + gc] = (CT)p;
          ps += p;
        }
        ps += __shfl_xor(ps, 1); ps += __shfl_xor(ps, 2);
        ps += __shfl_xor(ps, 4); ps += __shfl_xor(ps, 8);
        if (rr == 0) atomicAdd(sumrow + row, ps);
      }
    }
  }
}

// ---- Dispatch 1: prep (cvt5 + cvtT + pack_mask + zero sums). grid 12832. ----
__global__ __launch_bounds__(256) void prep_kernel(
    const float* __restrict__ x, const float* __restrict__ st,
    const float* __restrict__ Wq, const float* __restrict__ Wk,
    const float* __restrict__ Wp, const float* __restrict__ Wv,
    const int* __restrict__ mask,
    bf16* __restrict__ xb, bf16* __restrict__ stb, bf16* __restrict__ wqb,
    bf16* __restrict__ wkb, bf16* __restrict__ wpb, bf16* __restrict__ WvT,
    unsigned* __restrict__ mbits, float* __restrict__ sums)
{
  const int lin = blockIdx.x;
  const int t = threadIdx.x;
  if (lin < 10240) {
    const float* s; bf16* d;
    switch (lin >> 11) {
      case 0: s = x; d = xb; break;
      case 1: s = st; d = stb; break;
      case 2: s = Wq; d = wqb; break;
      case 3: s = Wk; d = wkb; break;
      default: s = Wp; d = wpb; break;
    }
    const int i = ((lin & 2047) * 256 + t) * 4;
    float4 v = *(const float4*)(s + i);
    bf16x4 o;
    o[0] = (bf16)v.x; o[1] = (bf16)v.y; o[2] = (bf16)v.z; o[3] = (bf16)v.w;
    *(bf16x4*)(d + i) = o;
  } else if (lin < 12288) {
    // WvT[h][d][e'] = Wv[h][e'][d]
    const int gid = (lin - 10240) * 256 + t;      // [0, 524288)
    const int e0 = (gid & 127) * 4;
    const int d = (gid >> 7) & 511;
    const int h = gid >> 16;
    const float* src = Wv + (size_t)h * 262144 + (size_t)e0 * 512 + d;
    bf16x4 o;
    o[0] = (bf16)src[0];
    o[1] = (bf16)src[512];
    o[2] = (bf16)src[1024];
    o[3] = (bf16)src[1536];
    *(bf16x4*)(WvT + (size_t)h * 262144 + (size_t)d * 512 + e0) = o;
  } else if (lin < 12800) {
    const int gid = (lin - 12288) * 256 + t;      // [0, 131072)
    const int* src = mask + (size_t)gid * 32;
    unsigned bits = 0;
#pragma unroll
    for (int j = 0; j < 32; j += 4) {
      int4 v = *(const int4*)(src + j);
      if (v.x) bits |= 1u << j;
      if (v.y) bits |= 1u << (j + 1);
      if (v.z) bits |= 1u << (j + 2);
      if (v.w) bits |= 1u << (j + 3);
    }
    mbits[gid] = bits;
  } else {
    const int i = ((lin - 12800) * 256 + t) * 4;  // [0, 32768) floats
    *(float4*)(sums + i) = make_float4(0.f, 0.f, 0.f, 0.f);
  }
}

// ---- Dispatch 2: proj (q/k projections + U = Wp_h.Wv_h). grid 2176. ----
__global__ __launch_bounds__(256) void proj_kernel(
    const bf16* __restrict__ xb, const bf16* __restrict__ stb,
    const bf16* __restrict__ wqb, const bf16* __restrict__ wkb,
    const bf16* __restrict__ wpb, const bf16* __restrict__ WvT,
    bf16* __restrict__ q, bf16* __restrict__ k, bf16* __restrict__ U)
{
  __shared__ bf16 As[128 * 64];
  __shared__ bf16 Bs[128 * 64];
  const int lin = blockIdx.x;
  if (lin < 2048) {
    const int g = ((lin >> 8) << 3) | (lin & 7);   // [0,64)
    const int tile = (lin >> 3) & 31;
    const int job = g >> 5;
    const int zz = g & 31;
    const size_t zb = zz >> 3, zh = zz & 7;
    const bf16* Ain = (job == 0) ? xb : stb;
    const bf16* W = (job == 0) ? wqb : wkb;
    bf16* Cout = (job == 0) ? q : k;
    gemm_body<bf16, 0>(As, Bs, Ain + zb * 524288, W + zh * 262144,
        Cout + zb * 4194304 + zh * 524288, 512, 512, 512, 512,
        (tile >> 2) * 128, (tile & 3) * 128, 1.0f, nullptr, nullptr);
  } else {
    const int lin2 = lin - 2048;                   // [0,128)
    const int h = lin2 >> 4;
    const int tile = lin2 & 15;
    gemm_body<bf16, 0>(As, Bs, wpb + (size_t)h * 512, WvT + (size_t)h * 262144,
        U + (size_t)h * 262144, 512, 4096, 512, 512,
        (tile >> 2) * 128, (tile & 3) * 128, 1.0f, nullptr, nullptr);
  }
}

// ---- Dispatch 3: big (scores+exp+rowsum, and VWT = U.states^T). grid 3072. ----
__global__ __launch_bounds__(256) void big_kernel(
    const bf16* __restrict__ q, const bf16* __restrict__ k,
    const bf16* __restrict__ U, const bf16* __restrict__ stb,
    bf16* __restrict__ P, bf16* __restrict__ VWT,
    const unsigned* __restrict__ mbits, float* __restrict__ sums, float scale)
{
  __shared__ bf16 As[128 * 64];
  __shared__ bf16 Bs[128 * 64];
  const int lin = blockIdx.x;
  if (lin < 2048) {
    // scores: z in [0,32), 64 tiles (8x8); same-z blocks on one XCD
    const int z = ((lin >> 9) << 3) | (lin & 7);
    const int j = (lin >> 3) & 63;
    const int zb = z >> 3, zh = z & 7;
    const bf16* A = q + (size_t)zb * 4194304 + (size_t)zh * 524288;
    const bf16* B = k + (size_t)zb * 4194304 + (size_t)zh * 524288;
    bf16* C = P + (size_t)zb * 8388608 + (size_t)zh * 1048576;
    const unsigned* mrow = mbits + ((size_t)zb << 15);
    float* sumrow = sums + ((size_t)z << 10);
    gemm_body<bf16, 1>(As, Bs, A, B, C, 512, 512, 512, 1024,
                       (j >> 3) * 128, (j & 7) * 128, scale, mrow, sumrow);
  } else {
    // VWT[b,h][e,s] = U_h . states_b^T : z in [0,32), 32 tiles (8 n x 4 m)
    const int lin2 = lin - 2048;
    const int z = ((lin2 >> 8) << 3) | (lin2 & 7);
    const int j = (lin2 >> 3) & 31;
    const int zb = z >> 3, zh = z & 7;
    gemm_body<bf16, 0>(As, Bs, U + (size_t)zh * 262144, stb + (size_t)zb * 524288,
        VWT + (size_t)zb * 4194304 + (size_t)zh * 524288, 512, 512, 512, 1024,
        (j >> 3) * 128, (j & 7) * 128, 1.0f, nullptr, nullptr);
  }
}

// ---- Dispatch 4: pvw — part8[h][b,l,e] = sinv_h ⊙ (P_{b,h} · VWT_{b,h}^T).
// grid 1024 (z=b*8+h in [0,32) XCD-grouped, 32 tiles = 8 l x 4 e). bf16 out. --
__global__ __launch_bounds__(256) void pvw_kernel(
    const bf16* __restrict__ P, const bf16* __restrict__ VWT,
    const float* __restrict__ sums, bf16* __restrict__ part8)
{
  __shared__ bf16 As[128 * 64];
  __shared__ bf16 Bs[128 * 64];
  const int lin = blockIdx.x;
  const int z = ((lin >> 8) << 3) | (lin & 7);    // [0,32)
  const int j = (lin >> 3) & 31;
  const int zb = z >> 3, zh = z & 7;
  const int m0 = (j >> 2) * 128, n0 = (j & 3) * 128;
  const int t = threadIdx.x;
  const int lane = t & 63, w = t >> 6;
  const int wm = w >> 1, wn = w & 1;
  const int srow = t >> 3, schunk = (t & 7) ^ (srow & 7);
  const int rr = lane & 15, q4 = lane >> 4;
  bf16* Als = As + t * 8;
  bf16* Bls = Bs + t * 8;

  const bf16* Ag = P + (size_t)zb * 8388608 + (size_t)zh * 1048576
                     + (size_t)(m0 + srow) * 1024 + schunk * 8;
  const bf16* Bg = VWT + (size_t)zb * 4194304 + (size_t)zh * 524288
                      + (size_t)(n0 + srow) * 1024 + schunk * 8;
  f32x4 acc[4][4] = {};
  for (int kt = 0; kt < 16; ++kt) {
    __syncthreads();
#pragma unroll
    for (int i = 0; i < 4; ++i) {
      gload_lds16(Ag + (size_t)(32 * i) * 1024, Als + i * 2048);
      gload_lds16(Bg + (size_t)(32 * i) * 1024, Bls + i * 2048);
    }
    Ag += 64; Bg += 64;
    __syncthreads();
#pragma unroll
    for (int kk = 0; kk < 2; ++kk) {
      bf16x8 af[4], bfr[4];
      const int ck = kk * 4 + q4;
#pragma unroll
      for (int r = 0; r < 4; ++r) {
        const int R = wm * 64 + r * 16 + rr;
        af[r] = *(const bf16x8*)(As + R * 64 + ((ck ^ (R & 7)) << 3));
      }
#pragma unroll
      for (int c = 0; c < 4; ++c) {
        const int R = wn * 64 + c * 16 + rr;
        bfr[c] = *(const bf16x8*)(Bs + R * 64 + ((ck ^ (R & 7)) << 3));
      }
#pragma unroll
      for (int r = 0; r < 4; ++r)
#pragma unroll
        for (int c = 0; c < 4; ++c)
          acc[r][c] = __builtin_amdgcn_mfma_f32_16x16x32_bf16(af[r], bfr[c], acc[r][c], 0, 0, 0);
    }
  }

  const float* srs = sums + ((size_t)z << 10);
  bf16* Cp = part8 + (size_t)zh * 2097152 + (size_t)zb * 524288;
#pragma unroll
  for (int r = 0; r < 4; ++r) {
#pragma unroll
    for (int i = 0; i < 4; ++i) {
      const int gr = m0 + wm * 64 + r * 16 + (q4 << 2) + i;
      const float inv = 1.0f / srs[gr];
#pragma unroll
      for (int c = 0; c < 4; ++c) {
        const int gc = n0 + wn * 64 + c * 16 + rr;
        Cp[(size_t)gr * 512 + gc] = (bf16)(acc[r][c][i] * inv);
      }
    }
  }
}

// ---- Dispatch 5: out = sum of 8 bf16 partials. grid 2048. ----
__global__ __launch_bounds__(256) void reduce8(
    const bf16* __restrict__ part8, float* __restrict__ out)
{
  const size_t i = ((size_t)blockIdx.x * 256 + threadIdx.x) * 4;
  float4 o = make_float4(0.f, 0.f, 0.f, 0.f);
#pragma unroll
  for (int s = 0; s < 8; ++s) {
    bf16x4 v = *(const bf16x4*)(part8 + (size_t)s * 2097152 + i);
    o.x += (float)v[0]; o.y += (float)v[1];
    o.z += (float)v[2]; o.w += (float)v[3];
  }
  *(float4*)(out + i) = o;
}

extern "C" void kernel_launch(void* const* d_in, const int* in_sizes, int n_in,
                              void* d_out, int out_size, void* d_ws, size_t ws_size,
                              hipStream_t stream) {
  const float* x    = (const float*)d_in[0];
  const float* st   = (const float*)d_in[1];
  const int*   mask = (const int*)d_in[2];
  const float* Wq   = (const float*)d_in[3];
  const float* Wk   = (const float*)d_in[4];
  const float* Wv   = (const float*)d_in[5];
  const float* Wp   = (const float*)d_in[6];
  float* out = (float*)d_out;

  char* ws = (char*)d_ws;
  const size_t MB = 1048576;
  bf16* xb  = (bf16*)(ws);               // 4MB
  bf16* stb = (bf16*)(ws + 4 * MB);      // 4MB
  bf16* wqb = (bf16*)(ws + 8 * MB);      // 4MB
  bf16* wkb = (bf16*)(ws + 12 * MB);     // 4MB
  bf16* wpb = (bf16*)(ws + 16 * MB);     // 4MB
  bf16* WvT = (bf16*)(ws + 20 * MB);     // 4MB [8,512,512] transposed
  bf16* U   = (bf16*)(ws + 24 * MB);     // 4MB [8,512,512] Wp_h.Wv_h
  bf16* q   = (bf16*)(ws + 28 * MB);     // 32MB; dead after big -> part8 overlays
  bf16* k   = (bf16*)(ws + 60 * MB);     // 32MB
  bf16* VWT = (bf16*)(ws + 92 * MB);     // 32MB [4,8,512,1024]
  bf16* P   = (bf16*)(ws + 124 * MB);    // 64MB [4,8,1024,1024] exp(scores)
  unsigned* mbits = (unsigned*)(ws + 188 * MB);  // 512KB
  float*    sums  = (float*)(ws + 189 * MB);     // 128KB
  bf16*     part8 = (bf16*)(ws + 28 * MB);       // 32MB = 8 x [4,1024,512] bf16

  dim3 blk(256);
  const float scale = 0.04419417382415922f;  // 1/sqrt(512)

  prep_kernel<<<dim3(12832), blk, 0, stream>>>(x, st, Wq, Wk, Wp, Wv, mask,
      xb, stb, wqb, wkb, wpb, WvT, mbits, sums);

  proj_kernel<<<dim3(2176), blk, 0, stream>>>(xb, stb, wqb, wkb, wpb, WvT,
      q, k, U);

  big_kernel<<<dim3(3072), blk, 0, stream>>>(q, k, U, stb, P, VWT,
      mbits, sums, scale);

  pvw_kernel<<<dim3(1024), blk, 0, stream>>>(P, VWT, sums, part8);

  reduce8<<<dim3(2048), blk, 0, stream>>>(part8, out);
}